// Round 5
// baseline (259.509 us; speedup 1.0000x reference)
//
#include <hip/hip_runtime.h>
#include <stdint.h>

typedef _Float16 v8h __attribute__((ext_vector_type(8)));
typedef _Float16 v4h __attribute__((ext_vector_type(4)));
typedef float v4f __attribute__((ext_vector_type(4)));

#define BB 4
#define LL 2048
#define TOPK 32
#define NF 416      // 16 pos + 16 R0 + 24*16 pair RBF
#define NOUT 128
#define NCAND 128
#define HBINS 512
#define HLO 1792    // bin window: (d_bits>>19) - HLO; covers d in [2^-15, 2^16)
#define FBS2 168    // Fb row stride in halves (336 B, 16B-aligned)

__device__ __constant__ int c_PA[24] = {0,2,3,4,1,1,1,1,0,0,0,4,4,3,0,2,3,4,2,3,4,2,3,2};
__device__ __constant__ int c_PB[24] = {0,2,3,4,0,2,3,4,2,3,4,2,3,2,1,1,1,1,0,0,0,4,4,3};

// ws layout (bytes)
#define OFF_ATOMS 0u            // B*L*16 f32 (4x float4/residue) = 524288 B
#define OFF_CA    524288u       // B*L float4                     = 131072 B
#define OFF_WT    655360u       // 128*416 f16                    = 106496 B

// np-bit-matched distance: ((dx*dx+dy*dy)+dz*dz)+1e-6, no fma, exact sqrt
static __device__ inline float dist_np(float4 a, float4 b) {
#pragma clang fp contract(off)
  float dx = a.x - b.x, dy = a.y - b.y, dz = a.z - b.z;
  float s = ((dx * dx + dy * dy) + dz * dz) + 1e-6f;
  return sqrtf(s);
}

static __device__ inline unsigned long long umin64(unsigned long long a, unsigned long long b) {
  return a < b ? a : b;
}
static __device__ inline unsigned long long umax64(unsigned long long a, unsigned long long b) {
  return a > b ? a : b;
}

static __device__ inline void rbf16(float d, _Float16* dst) {
  v8h h0, h1;
#pragma unroll
  for (int m = 0; m < 16; ++m) {
    float mu = 2.0f + (20.0f / 15.0f) * (float)m;  // folded at compile time
    float a = (d - mu) * 0.8f;
    float v = __expf(-a * a);
    if (m < 8) h0[m] = (_Float16)v;
    else h1[m - 8] = (_Float16)v;
  }
  *(v8h*)dst = h0;
  *(v8h*)(dst + 8) = h1;
}

static __device__ inline float dist3(const float* a, const float* b) {
  float dx = a[0] - b[0], dy = a[1] - b[1], dz = a[2] - b[2];
  return sqrtf(dx * dx + dy * dy + dz * dz + 1e-6f);
}

// ---------------- prep: atoms (4x float4 rows), compact Ca float4, W_edge -> f16 T ----------------
__global__ __launch_bounds__(256) void prep_kernel(const float* __restrict__ X,
                                                   const float* __restrict__ W_edge,
                                                   float4* __restrict__ atomsP,
                                                   float4* __restrict__ CaP,
                                                   _Float16* __restrict__ Wt) {
  int idx = blockIdx.x * 256 + threadIdx.x;
  if (idx < BB * LL) {
    const float* xp = X + (size_t)idx * 12;
    float Nx = xp[0], Ny = xp[1], Nz = xp[2];
    float Cax = xp[3], Cay = xp[4], Caz = xp[5];
    float Cx = xp[6], Cy = xp[7], Cz = xp[8];
    float Ox = xp[9], Oy = xp[10], Oz = xp[11];
    float bx = Cax - Nx, by = Cay - Ny, bz = Caz - Nz;
    float cx = Cx - Cax, cy = Cy - Cay, cz = Cz - Caz;
    float ax = by * cz - bz * cy;
    float ay = bz * cx - bx * cz;
    float az = bx * cy - by * cx;
    float Cbx = -0.58273431f * ax + 0.56802827f * bx - 0.54067466f * cx + Cax;
    float Cby = -0.58273431f * ay + 0.56802827f * by - 0.54067466f * cy + Cay;
    float Cbz = -0.58273431f * az + 0.56802827f * bz - 0.54067466f * cz + Caz;
    // layout: [N(3) Ca(3) C(3) O(3) Cb(3) pad]
    atomsP[(size_t)idx * 4 + 0] = make_float4(Nx, Ny, Nz, Cax);
    atomsP[(size_t)idx * 4 + 1] = make_float4(Cay, Caz, Cx, Cy);
    atomsP[(size_t)idx * 4 + 2] = make_float4(Cz, Ox, Oy, Oz);
    atomsP[(size_t)idx * 4 + 3] = make_float4(Cbx, Cby, Cbz, 0.f);
    CaP[idx] = make_float4(Cax, Cay, Caz, 0.f);
  } else {
    int t = idx - BB * LL;
    if (t < NOUT * NF) {
      int n = t / NF;
      int k = t - n * NF;
      Wt[t] = (_Float16)W_edge[(size_t)k * NOUT + n];  // Wt[n][k] = W_edge[k][n]
    }
  }
}

// ---------------- top-32: one wave per query row, windowed radix-select + bitonic ----------------
// Selection logic identical to the passing round-4 version (same key, same fp op order,
// same crossing-bin semantics) — only the parallel decomposition changed.
__global__ __launch_bounds__(256) void topk_kernel(const float4* __restrict__ CaP,
                                                   float* __restrict__ outIdx) {
  __shared__ int hist[4][HBINS];
  __shared__ unsigned long long cand[4][NCAND];
  __shared__ int cnt[4];
  __shared__ int cbs[4];
  int tid = threadIdx.x;
  int lane = tid & 63, w = tid >> 6;
  int bid = blockIdx.x;                 // 2048 blocks, 4 rows each
  int row = bid * 4 + w;
  int b = row >> 11;
  int i = row & (LL - 1);
  const float4* Cb_ = CaP + (size_t)b * LL;

  for (int t = lane; t < HBINS; t += 64) hist[w][t] = 0;
  cand[w][lane] = ~0ull;
  cand[w][lane + 64] = ~0ull;
  if (lane == 0) cnt[w] = 0;
  float4 ci = Cb_[i];
  __syncthreads();

  // pass 1: bin counts (32 keys/lane)
  for (int t = 0; t < 32; ++t) {
    int j = (t << 6) | lane;
    float d = dist_np(ci, Cb_[j]);
    int bin = (int)(__float_as_uint(d) >> 19) - HLO;
    bin = bin < 0 ? 0 : (bin > HBINS - 1 ? HBINS - 1 : bin);
    atomicAdd(&hist[w][bin], 1);
  }
  __syncthreads();

  // scan: 8 bins/lane, wave inclusive scan, find crossing bin
  {
    int base = lane * 8;
    int h[8], psum = 0;
#pragma unroll
    for (int t = 0; t < 8; ++t) { h[t] = hist[w][base + t]; psum += h[t]; }
    int incl = psum;
#pragma unroll
    for (int off = 1; off < 64; off <<= 1) {
      int o = __shfl_up(incl, off);
      if (lane >= off) incl += o;
    }
    int excl = incl - psum;
    if (excl < TOPK && incl >= TOPK) {
      int run = excl;
#pragma unroll
      for (int t = 0; t < 8; ++t) {
        if (run < TOPK && run + h[t] >= TOPK) { cbs[w] = base + t; break; }
        run += h[t];
      }
    }
  }
  __syncthreads();
  int cb = cbs[w];

  // pass 2: recompute, collect keys with bin <= cb (>= 32 by construction)
  for (int t = 0; t < 32; ++t) {
    int j = (t << 6) | lane;
    float d = dist_np(ci, Cb_[j]);
    int bin = (int)(__float_as_uint(d) >> 19) - HLO;
    bin = bin < 0 ? 0 : (bin > HBINS - 1 ? HBINS - 1 : bin);
    if (bin <= cb) {
      int slot = atomicAdd(&cnt[w], 1);
      if (slot < NCAND)
        cand[w][slot] = ((unsigned long long)__float_as_uint(d) << 32) | (unsigned)j;
    }
  }
  __syncthreads();

  // per-wave bitonic sort of 128 candidates (2/lane), write top-32
  {
    unsigned long long x = cand[w][lane];
    unsigned long long y = cand[w][lane + 64];
#pragma unroll
    for (int k = 2; k <= 128; k <<= 1) {
#pragma unroll
      for (int j = 64; j >= 1; j >>= 1) {
        if (j >= k) continue;
        if (j == 64) {
          unsigned long long mn = umin64(x, y), mx = umax64(x, y);
          x = mn; y = mx;
        } else {
          unsigned long long px = __shfl_xor(x, j);
          bool upx = ((lane & k) == 0);
          bool lowx = ((lane & j) == 0);
          x = (lowx == upx) ? umin64(x, px) : umax64(x, px);
          unsigned long long py = __shfl_xor(y, j);
          bool upy = (((lane + 64) & k) == 0);
          y = (lowx == upy) ? umin64(y, py) : umax64(y, py);
        }
      }
    }
    if (lane < TOPK) {
      int j = (int)(x & 0xffffffffull);
      outIdx[(size_t)row * TOPK + lane] = (float)j;  // harness reads flat f32
    }
  }
}

// ---------------- 4 residues/block: features -> f16 MFMA GEMM (3 K-chunks) -> LayerNorm ----------------
__global__ __launch_bounds__(512, 6) void edge_kernel(
    const float4* __restrict__ atomsP,
    const _Float16* __restrict__ Wt, const float* __restrict__ outIdxF,
    const int* __restrict__ ridx, const int* __restrict__ chain,
    const float* __restrict__ W_pos, const float* __restrict__ b_pos,
    const float* __restrict__ gamma, const float* __restrict__ beta,
    float* __restrict__ outE) {
  __shared__ __align__(16) _Float16 Fb[128][FBS2];   // 43008 B
  __shared__ __align__(16) char scratch[8704];       // na_f, later partS/partQ/mr
  __shared__ float qa_f[4][16];
  __shared__ int dpos_s[128];
  __shared__ int nidx_s[128];
  float (*na_f)[17] = (float (*)[17])scratch;        // neighbor atoms (anti-conflict stride)
  float (*partS)[5] = (float (*)[5])scratch;         // overlay: na_f dead after fills
  float (*partQ)[5] = (float (*)[5])(scratch + 2560);
  float2* mr = (float2*)(scratch + 5120);

  int bid = blockIdx.x;          // group of 4 residues
  int b = bid >> 9;
  int tid = threadIdx.x;
  int g0 = bid * 4;

  if (tid < 128) {
    int r = tid >> 5;
    int j = (int)outIdxF[(size_t)bid * 128 + tid];
    nidx_s[tid] = j;
    int ri = ridx[g0 + r], rj = ridx[b * LL + j];
    int off = ri - rj + 32;
    off = off < 0 ? 0 : (off > 64 ? 64 : off);
    dpos_s[tid] = (chain[g0 + r] == chain[b * LL + j]) ? off : 65;
  } else if (tid < 144) {
    int q16 = tid - 128;
    int r = q16 >> 2, q = q16 & 3;
    float4 v = atomsP[(size_t)(g0 + r) * 4 + q];
    qa_f[r][q * 4 + 0] = v.x; qa_f[r][q * 4 + 1] = v.y;
    qa_f[r][q * 4 + 2] = v.z; qa_f[r][q * 4 + 3] = v.w;
  }
  __syncthreads();

  int e = tid >> 2, g = tid & 3;
  int rr = e >> 5;
  {  // neighbor atoms: one coalesced float4/thread
    float4 v = atomsP[((size_t)b * LL + nidx_s[e]) * 4 + g];
    na_f[e][g * 4 + 0] = v.x; na_f[e][g * 4 + 1] = v.y;
    na_f[e][g * 4 + 2] = v.z; na_f[e][g * 4 + 3] = v.w;
  }

  // helper lambda for pair distance from LDS atoms
  auto pdist = [&](int ee, int pp) -> float {
    int ia = c_PA[pp] * 3, ib = c_PB[pp] * 3;
    const float* qa = qa_f[rr];
    const float* nb = na_f[ee];
    float dx = qa[ia] - nb[ib];
    float dy = qa[ia + 1] - nb[ib + 1];
    float dz = qa[ia + 2] - nb[ib + 2];
    return sqrtf(dx * dx + dy * dy + dz * dz + 1e-6f);
  };

  // ---- fill chunk0: cols 0..127 = pos(16) + R0(16) + pairs 0..5 ----
  {
    int dp = dpos_s[e];
    v4h hp;
#pragma unroll
    for (int t = 0; t < 4; ++t)
      hp[t] = (_Float16)(W_pos[dp * 16 + g * 4 + t] + b_pos[g * 4 + t]);
    *(v4h*)&Fb[e][g * 4] = hp;
  }
  for (int s = g; s < 7; s += 4) {
    float d = (s == 0) ? dist3(&qa_f[rr][3], &na_f[e][3])   // R0: Ca-Ca (feeds RBF only)
                       : pdist(e, s - 1);
    rbf16(d, &Fb[e][16 + s * 16]);
  }
  __syncthreads();

  // ---- GEMM: waves (mt: 64 rows) x (nh: 32 cols); acc carried across 3 chunks ----
  int lane = tid & 63, wv = tid >> 6;
  int mt = wv & 1, nh = wv >> 1;
  int lm = lane & 15, lq = lane >> 4;
  const _Float16* bp0 = Wt + (size_t)(nh * 32 + lm) * NF + lq * 8;
  const _Float16* bp1 = bp0 + 16 * NF;
  v4f acc[4][2];
#pragma unroll
  for (int t = 0; t < 4; ++t) { acc[t][0] = (v4f){0,0,0,0}; acc[t][1] = (v4f){0,0,0,0}; }

#pragma unroll
  for (int kk = 0; kk < 4; ++kk) {  // chunk0: K=128
    int k = kk * 32;
    v8h B0 = *(const v8h*)(bp0 + k);
    v8h B1 = *(const v8h*)(bp1 + k);
#pragma unroll
    for (int t = 0; t < 4; ++t) {
      v8h A = *(const v8h*)&Fb[mt * 64 + t * 16 + lm][lq * 8 + k];
      acc[t][0] = __builtin_amdgcn_mfma_f32_16x16x32_f16(A, B0, acc[t][0], 0, 0, 0);
      acc[t][1] = __builtin_amdgcn_mfma_f32_16x16x32_f16(A, B1, acc[t][1], 0, 0, 0);
    }
  }
  __syncthreads();

  // ---- fill chunk1: pairs 6..13 at local cols s*16 ----
  for (int s = g; s < 8; s += 4) {
    rbf16(pdist(e, 6 + s), &Fb[e][s * 16]);
  }
  __syncthreads();

#pragma unroll
  for (int kk = 0; kk < 4; ++kk) {  // chunk1: K=128, global k offset 128
    int k = kk * 32;
    v8h B0 = *(const v8h*)(bp0 + 128 + k);
    v8h B1 = *(const v8h*)(bp1 + 128 + k);
#pragma unroll
    for (int t = 0; t < 4; ++t) {
      v8h A = *(const v8h*)&Fb[mt * 64 + t * 16 + lm][lq * 8 + k];
      acc[t][0] = __builtin_amdgcn_mfma_f32_16x16x32_f16(A, B0, acc[t][0], 0, 0, 0);
      acc[t][1] = __builtin_amdgcn_mfma_f32_16x16x32_f16(A, B1, acc[t][1], 0, 0, 0);
    }
  }
  __syncthreads();

  // ---- fill chunk2: pairs 14..23 at local cols s*16 ----
  for (int s = g; s < 10; s += 4) {
    rbf16(pdist(e, 14 + s), &Fb[e][s * 16]);
  }
  __syncthreads();

#pragma unroll
  for (int kk = 0; kk < 5; ++kk) {  // chunk2: K=160, global k offset 256
    int k = kk * 32;
    v8h B0 = *(const v8h*)(bp0 + 256 + k);
    v8h B1 = *(const v8h*)(bp1 + 256 + k);
#pragma unroll
    for (int t = 0; t < 4; ++t) {
      v8h A = *(const v8h*)&Fb[mt * 64 + t * 16 + lm][lq * 8 + k];
      acc[t][0] = __builtin_amdgcn_mfma_f32_16x16x32_f16(A, B0, acc[t][0], 0, 0, 0);
      acc[t][1] = __builtin_amdgcn_mfma_f32_16x16x32_f16(A, B1, acc[t][1], 0, 0, 0);
    }
  }

  // ---- LayerNorm: per-row 32-col partials -> LDS (overlaid) -> combine -> store ----
#pragma unroll
  for (int t = 0; t < 4; ++t) {
#pragma unroll
    for (int r = 0; r < 4; ++r) {
      float s = acc[t][0][r] + acc[t][1][r];
      float q = acc[t][0][r] * acc[t][0][r] + acc[t][1][r] * acc[t][1][r];
#pragma unroll
      for (int off = 1; off <= 8; off <<= 1) {
        s += __shfl_xor(s, off);
        q += __shfl_xor(q, off);
      }
      if (lm == 0) {
        int row = mt * 64 + t * 16 + lq * 4 + r;
        partS[row][nh] = s;
        partQ[row][nh] = q;
      }
    }
  }
  __syncthreads();
  if (tid < 128) {
    float S = (partS[tid][0] + partS[tid][1]) + (partS[tid][2] + partS[tid][3]);
    float Q = (partQ[tid][0] + partQ[tid][1]) + (partQ[tid][2] + partQ[tid][3]);
    float mean = S * (1.0f / 128.0f);
    float var = Q * (1.0f / 128.0f) - mean * mean;
    mr[tid] = make_float2(mean, 1.0f / sqrtf(var + 1e-5f));
  }
  __syncthreads();
  float gm0 = gamma[nh * 32 + lm], gm1 = gamma[nh * 32 + 16 + lm];
  float bt0 = beta[nh * 32 + lm], bt1 = beta[nh * 32 + 16 + lm];
  float* op = outE + (size_t)bid * 128 * NOUT + nh * 32 + lm;
#pragma unroll
  for (int t = 0; t < 4; ++t) {
#pragma unroll
    for (int r = 0; r < 4; ++r) {
      int row = mt * 64 + t * 16 + lq * 4 + r;
      float2 m = mr[row];
      float* p = op + (size_t)row * NOUT;
      p[0]  = (acc[t][0][r] - m.x) * m.y * gm0 + bt0;
      p[16] = (acc[t][1][r] - m.x) * m.y * gm1 + bt1;
    }
  }
}

extern "C" void kernel_launch(void* const* d_in, const int* in_sizes, int n_in,
                              void* d_out, int out_size, void* d_ws, size_t ws_size,
                              hipStream_t stream) {
  const float* X = (const float*)d_in[0];
  const int* ridx = (const int*)d_in[2];
  const int* chain = (const int*)d_in[3];
  const float* W_pos = (const float*)d_in[4];
  const float* b_pos = (const float*)d_in[5];
  const float* W_edge = (const float*)d_in[6];
  const float* gamma = (const float*)d_in[7];
  const float* beta = (const float*)d_in[8];

  float* outE = (float*)d_out;
  float* outIdx = outE + (size_t)BB * LL * TOPK * NOUT;

  char* ws = (char*)d_ws;
  float4* atomsP = (float4*)(ws + OFF_ATOMS);
  float4* CaP = (float4*)(ws + OFF_CA);
  _Float16* Wt = (_Float16*)(ws + OFF_WT);

  prep_kernel<<<240, 256, 0, stream>>>(X, W_edge, atomsP, CaP, Wt);
  topk_kernel<<<BB * LL / 4, 256, 0, stream>>>(CaP, outIdx);
  edge_kernel<<<BB * LL / 4, 512, 0, stream>>>(atomsP, Wt, outIdx, ridx, chain,
                                               W_pos, b_pos, gamma, beta, outE);
}